// Round 12
// baseline (614.650 us; speedup 1.0000x reference)
//
#include <hip/hip_runtime.h>
#include <hip/hip_bf16.h>

#define NG 100000
#define ND 50000
#define NC 2000
#define NF 5000
#define DD 64

#define BSH 9
#define BINW 512
#define NREL 6
#define NB_CG ((NG + BINW - 1) / BINW)
#define NB_GC ((ND + BINW - 1) / BINW)
#define NB_CP ((NC + BINW - 1) / BINW)
#define NB_PC ((ND + BINW - 1) / BINW)
#define NB_GF ((NF + BINW - 1) / BINW)
#define NB_FG ((NG + BINW - 1) / BINW)
#define TOTB (NB_CG + NB_GC + NB_CP + NB_PC + NB_GF + NB_FG)
#define CHUNK 4096
#define NSLOT 128

typedef _Float16 h2_t __attribute__((ext_vector_type(2)));
typedef _Float16 half8 __attribute__((ext_vector_type(8)));
typedef float f32x4 __attribute__((ext_vector_type(4)));
typedef float f32x2 __attribute__((ext_vector_type(2)));
typedef unsigned char uchar;

__device__ inline uint packh2_rne(float a, float b) {
    h2_t h; h.x = (_Float16)a; h.y = (_Float16)b;
    return __builtin_bit_cast(uint, h);
}
__device__ inline uint packh2(float a, float b) {  // RTZ, 1 instr
    return __builtin_bit_cast(uint, __builtin_amdgcn_cvt_pkrtz(a, b));
}
__device__ inline float2 h2f2(uint u) {
    h2_t h = __builtin_bit_cast(h2_t, u);
    return make_float2((float)h.x, (float)h.y);
}
__device__ inline float fdot2u(uint m, uint w, float acc) {
#if __has_builtin(__builtin_amdgcn_fdot2)
    return __builtin_amdgcn_fdot2(__builtin_bit_cast(h2_t, m),
                                  __builtin_bit_cast(h2_t, w), acc, false);
#else
    float2 a = h2f2(m), b = h2f2(w);
    return acc + a.x * b.x + a.y * b.y;
#endif
}

// ---- fp8 e4m3: hardware cvt when available (device pass), sw fallback ----
#if __has_builtin(__builtin_amdgcn_cvt_pk_f32_fp8) && __has_builtin(__builtin_amdgcn_cvt_pk_fp8_f32)
template <bool HI>
__device__ inline f32x2 dec_pk8(uint u) {
    return __builtin_amdgcn_cvt_pk_f32_fp8(u, HI);
}
__device__ inline uint enc2_fp8(float a, float b) {
    return __builtin_amdgcn_cvt_pk_fp8_f32(a, b, 0u, false) & 0xffffu;
}
__device__ inline uint enc1_fp8(float a) {
    return __builtin_amdgcn_cvt_pk_fp8_f32(a, a, 0u, false) & 0xffu;
}
#else
template <bool HI>
__device__ inline f32x2 dec_pk8(uint u) {
    uint pair = HI ? (u >> 16) : (u & 0xffffu);
    uint b0 = pair & 0xffu, b1 = (pair >> 8) & 0xffu;
    ushort h0 = (ushort)(((b0 & 0x80u) << 8) | ((b0 & 0x7fu) << 7));
    ushort h1 = (ushort)(((b1 & 0x80u) << 8) | ((b1 & 0x7fu) << 7));
    f32x2 r;
    r.x = 256.f * (float)__builtin_bit_cast(_Float16, h0);
    r.y = 256.f * (float)__builtin_bit_cast(_Float16, h1);
    return r;
}
__device__ inline uint enc1_fp8(float x) {
    ushort h = __builtin_bit_cast(ushort, (_Float16)(x * 0.00390625f));
    uint mag = h & 0x7fffu;
    uint r = (mag + 0x3fu + ((mag >> 7) & 1u)) >> 7;
    if (r > 0x7eu) r = 0x7eu;
    return r | ((h >> 8) & 0x80u);
}
__device__ inline uint enc2_fp8(float a, float b) {
    return enc1_fp8(a) | (enc1_fp8(b) << 8);
}
#endif

// ---------------------------------------------------------------------------
struct Cvt4 { const float* in[4]; uint* out[4]; ushort* out8[4]; int n2[4]; };
struct EdgeJobs {
    const int* src[NREL]; const int* dst[NREL];
    int binbase[NREL]; int E[NREL]; int blk_end[NREL];
};
struct BPackJobs {
    const float* A[6]; const float* B[6]; const float* Ra[6]; const float* Rb[6];
    uint4* out[6]; int nkt[6];
};

// ---------------------------------------------------------------------------
// Mega pass A: edge bin-histogram | f32->{f16,fp8} table cvt | Wc1 pack |
// MFMA B-image packs.
struct MegaA {
    EdgeJobs ej; Cvt4 cv; BPackJobs bp;
    const float* Wc1; uint2* pwWc1;
    int hist_blocks, cvt_blocks;
    int* ghist;
};
__global__ __launch_bounds__(256) void megaA_kernel(MegaA a) {
    int b = blockIdx.x;
    if (b < a.hist_blocks) {
        __shared__ int lh[TOTB];
        for (int t = threadIdx.x; t < TOTB; t += 256) lh[t] = 0;
        __syncthreads();
        int j = 0;
        while (b >= a.ej.blk_end[j]) ++j;
        int b0 = j ? a.ej.blk_end[j - 1] : 0;
        int e0 = (b - b0) * CHUNK;
        const int* dst = a.ej.dst[j];
        int E = a.ej.E[j], bb = a.ej.binbase[j];
        for (int t = threadIdx.x; t < CHUNK; t += 256) {
            int e = e0 + t;
            if (e < E) atomicAdd(&lh[bb + (dst[e] >> BSH)], 1);
        }
        __syncthreads();
        for (int t = threadIdx.x; t < TOTB; t += 256)
            if (lh[t]) atomicAdd(&a.ghist[t], lh[t]);
    } else if (b < a.hist_blocks + a.cvt_blocks) {
        int cb = b - a.hist_blocks;
        for (int j = 0; j < 4; ++j) {
            int n2 = a.cv.n2[j];
            const float2* ip = (const float2*)a.cv.in[j];
            uint* op = a.cv.out[j];
            ushort* o8 = a.cv.out8[j];
            for (int i = cb * 256 + threadIdx.x; i < n2; i += a.cvt_blocks * 256) {
                float2 v = ip[i];
                op[i] = packh2_rne(v.x, v.y);
                if (o8) o8[i] = (ushort)enc2_fp8(v.x, v.y);
            }
        }
    } else if (b == a.hist_blocks + a.cvt_blocks) {
        const float* A = a.Wc1;
        uint2* o = a.pwWc1;
        for (int t = threadIdx.x; t < 32 * 64; t += 256) {
            int k4 = t >> 6, c = t & 63;
            float v0 = A[(4 * k4 + 0) * 64 + c];
            float v1 = A[(4 * k4 + 1) * 64 + c];
            float v2 = A[(4 * k4 + 2) * 64 + c];
            float v3 = A[(4 * k4 + 3) * 64 + c];
            o[t] = make_uint2(packh2_rne(v0, v1), packh2_rne(v2, v3));
        }
    } else {
        int pj = b - a.hist_blocks - a.cvt_blocks - 1;
        const float* A = a.bp.A[pj];
        const float* B = a.bp.B[pj];
        const float* Ra = a.bp.Ra[pj];
        const float* Rb = a.bp.Rb[pj];
        uint4* o = a.bp.out[pj];
        int n = a.bp.nkt[pj] * 4 * 64;
        for (int t = threadIdx.x; t < n; t += 256) {
            int kt = t >> 8, nt = (t >> 6) & 3, l = t & 63;
            int col = nt * 16 + (l & 15);
            float v[8];
#pragma unroll
            for (int j = 0; j < 8; ++j) {
                int k = kt * 32 + ((l >> 4) << 3) + j;
                int sel = k >> 6, r = k & 63;
                float x;
                if (sel == 0) x = A[r * 64 + col];
                else if (sel == 1 && B) x = B[r * 64 + col];
                else x = Ra[r * 64 + col] + (Rb ? Rb[r * 64 + col] : 0.f);
                v[j] = x;
            }
            o[t] = make_uint4(packh2_rne(v[0], v[1]), packh2_rne(v[2], v[3]),
                              packh2_rne(v[4], v[5]), packh2_rne(v[6], v[7]));
        }
    }
}

// ---------------------------------------------------------------------------
// Pass B: exclusive scan of bin counts (1 block, wave 0)
__global__ void scanB_kernel(const int* __restrict__ ghist, int* __restrict__ gbinstart,
                             int* __restrict__ gcursor) {
    int lane = threadIdx.x;
    if (lane >= 64) return;
    int carry = 0;
    for (int base = 0; base < TOTB; base += 64) {
        int idx = base + lane;
        int v = (idx < TOTB) ? ghist[idx] : 0;
        int ts = v;
        for (int d = 1; d < 64; d <<= 1) { int t = __shfl_up(ts, d); if (lane >= d) ts += t; }
        int excl = carry + ts - v;
        if (idx < TOTB) { gbinstart[idx] = excl; gcursor[idx] = excl; }
        carry += __shfl(ts, 63);
    }
    if (lane == 0) gbinstart[TOTB] = carry;
}

// ---------------------------------------------------------------------------
// Pass C: binned scatter of packed (src<<9 | dstLocal)
__global__ __launch_bounds__(256) void scatC_kernel(EdgeJobs ej, int* __restrict__ gcursor,
                                                    int* __restrict__ binned) {
    __shared__ int lh[TOTB], lbase[TOTB];
    for (int t = threadIdx.x; t < TOTB; t += 256) lh[t] = 0;
    __syncthreads();
    int b = blockIdx.x, j = 0;
    while (b >= ej.blk_end[j]) ++j;
    int b0 = j ? ej.blk_end[j - 1] : 0;
    int e0 = (b - b0) * CHUNK;
    const int* dst = ej.dst[j];
    const int* srcp = ej.src[j];
    int E = ej.E[j], bb = ej.binbase[j];
    for (int t = threadIdx.x; t < CHUNK; t += 256) {
        int e = e0 + t;
        if (e < E) atomicAdd(&lh[bb + (dst[e] >> BSH)], 1);
    }
    __syncthreads();
    for (int t = threadIdx.x; t < TOTB; t += 256) {
        int c = lh[t];
        if (c) { lbase[t] = atomicAdd(&gcursor[t], c); lh[t] = 0; }
    }
    __syncthreads();
    for (int t = threadIdx.x; t < CHUNK; t += 256) {
        int e = e0 + t;
        if (e < E) {
            int d = dst[e];
            int bin = bb + (d >> BSH);
            int p = atomicAdd(&lh[bin], 1);
            binned[lbase[bin] + p] = (srcp[e] << BSH) | (d & (BINW - 1));
        }
    }
}

// ---------------------------------------------------------------------------
// Pass D: per-bin exact CSR
struct BinMeta { int relbase[NREL + 1]; int* off[NREL]; int ndst[NREL]; };
__global__ __launch_bounds__(256) void csrD_kernel(BinMeta bmt, const int* __restrict__ gbinstart,
                                                   const int* __restrict__ binned,
                                                   int* __restrict__ adj) {
    __shared__ int lcnt[BINW], lexc[BINW];
    int b = blockIdx.x, j = 0;
    while (b >= bmt.relbase[j + 1]) ++j;
    int lb = b - bmt.relbase[j];
    int n0 = lb << BSH;
    int nn = bmt.ndst[j] - n0; if (nn > BINW) nn = BINW;
    int es = gbinstart[b], ee = gbinstart[b + 1];
    for (int t = threadIdx.x; t < BINW; t += 256) lcnt[t] = 0;
    __syncthreads();
    for (int t = es + threadIdx.x; t < ee; t += 256)
        atomicAdd(&lcnt[binned[t] & (BINW - 1)], 1);
    __syncthreads();
    if (threadIdx.x < 64) {
        int lane = threadIdx.x, carry = 0;
        for (int base = 0; base < BINW; base += 64) {
            int v = lcnt[base + lane];
            int ts = v;
            for (int d = 1; d < 64; d <<= 1) { int t2 = __shfl_up(ts, d); if (lane >= d) ts += t2; }
            lexc[base + lane] = carry + ts - v;
            carry += __shfl(ts, 63);
        }
    }
    __syncthreads();
    int* off = bmt.off[j];
    for (int t = threadIdx.x; t < nn; t += 256) off[n0 + t] = es + lexc[t];
    if (threadIdx.x == 0 && n0 + nn == bmt.ndst[j]) off[bmt.ndst[j]] = ee;
    for (int t = threadIdx.x; t < BINW; t += 256) lcnt[t] = 0;
    __syncthreads();
    for (int t = es + threadIdx.x; t < ee; t += 256) {
        int v = binned[t];
        int dl = v & (BINW - 1);
        int p = atomicAdd(&lcnt[dl], 1);
        adj[es + lexc[dl] + p] = v >> BSH;
    }
}

// ---------------------------------------------------------------------------
// gather v5: XCD-segregated scheduling (blockIdx&7 = XCD heuristic; perf-only).
// mode 0 (pair, fp8 64B rows): f32 accumulate, 4-deep clamped ILP.
// mode 1 (oct, fp16 128B rows): pk-f16 accumulate.
struct GJob { const int* off; const void* x; uint4* cat; int cstr, colbase, n, mode; };
struct GSched {
    GJob jb[6];
    int gjobs[2][4];   // job id per (group, range); -1 = none
    int gend[2][4];    // cumulative slot ends (last == NSLOT)
};

__device__ inline void acc8(uint2 v, float* s) {
    f32x2 p01 = dec_pk8<false>(v.x), p23 = dec_pk8<true>(v.x);
    f32x2 p45 = dec_pk8<false>(v.y), p67 = dec_pk8<true>(v.y);
    s[0] += p01.x; s[1] += p01.y; s[2] += p23.x; s[3] += p23.y;
    s[4] += p45.x; s[5] += p45.y; s[6] += p67.x; s[7] += p67.y;
}

__global__ __launch_bounds__(256) void gather_kernel(GSched g, const int* __restrict__ adj) {
    int b = blockIdx.x;
    int xcd = b & 7, slot = b >> 3;
    int grp = xcd >> 2;
    int k = 0;
    while (k < 3 && slot >= g.gend[grp][k]) ++k;
    int j = g.gjobs[grp][k];
    if (j < 0) return;
    int s0 = k ? g.gend[grp][k - 1] : 0;
    int W = 4 * (g.gend[grp][k] - s0);
    int worker = (xcd & 3) + 4 * (slot - s0);
    GJob jb = g.jb[j];
    int tid = threadIdx.x, w = tid >> 6, lane = tid & 63;
    int cq = lane & 7, rg = lane >> 3;
    int start = worker * 4 + w, stride = W * 4;
    if (jb.mode == 0) {
        const uint2* x8 = (const uint2*)jb.x;
        int side = rg >> 2, sub = rg & 3;
        int npair = (jb.n + 1) >> 1;
        for (int p = start; p < npair; p += stride) {
            int ia = p * 2;
            bool hb = (ia + 1 < jb.n);
            int a0 = jb.off[ia], a1 = jb.off[ia + 1];
            int b1 = hb ? jb.off[ia + 2] : a1;
            int cnt = side ? (b1 - a1) : (a1 - a0);
            const int* base = adj + (side ? a1 : a0);
            float s[8] = {0, 0, 0, 0, 0, 0, 0, 0};
            int l = cnt - 1;
            for (int jj = 0; jj < cnt; jj += 16) {
                int e0 = jj + sub, e1 = e0 + 4, e2 = e0 + 8, e3 = e0 + 12;
                int i0 = base[e0 < l ? e0 : l];
                int i1 = base[e1 < l ? e1 : l];
                int i2 = base[e2 < l ? e2 : l];
                int i3 = base[e3 < l ? e3 : l];
                uint2 v0 = x8[(long long)i0 * 8 + cq];
                uint2 v1 = x8[(long long)i1 * 8 + cq];
                uint2 v2 = x8[(long long)i2 * 8 + cq];
                uint2 v3 = x8[(long long)i3 * 8 + cq];
                if (e0 < cnt) acc8(v0, s);
                if (e1 < cnt) acc8(v1, s);
                if (e2 < cnt) acc8(v2, s);
                if (e3 < cnt) acc8(v3, s);
            }
#pragma unroll
            for (int q = 0; q < 8; ++q) {
                s[q] += __shfl_xor(s[q], 8);
                s[q] += __shfl_xor(s[q], 16);
            }
            float invf = 1.f / fmaxf((float)cnt, 1.f);
            if (sub == 0 && (side == 0 || hb)) {
                int node = ia + side;
                uint4 o = make_uint4(packh2(s[0] * invf, s[1] * invf),
                                     packh2(s[2] * invf, s[3] * invf),
                                     packh2(s[4] * invf, s[5] * invf),
                                     packh2(s[6] * invf, s[7] * invf));
                jb.cat[(long long)node * jb.cstr + jb.colbase + cq] = o;
            }
        }
    } else {
        const uint4* x16 = (const uint4*)jb.x;
        for (int gp = start; gp * 8 < jb.n; gp += stride) {
            int node = gp * 8 + rg;
            int nc = node < jb.n ? node : jb.n - 1;
            int o0 = jb.off[nc], o1 = jb.off[nc + 1];
            int cnt = (node < jb.n) ? (o1 - o0) : 0;
            half8 acc = {0, 0, 0, 0, 0, 0, 0, 0};
            for (int t = 0; t < cnt; ++t) {
                int idx = adj[o0 + t];
                acc += __builtin_bit_cast(half8, x16[(long long)idx * 8 + cq]);
            }
            float invf = 1.f / fmaxf((float)cnt, 1.f);
            _Float16 ih = (_Float16)invf;
            half8 iv = {ih, ih, ih, ih, ih, ih, ih, ih};
            acc *= iv;
            if (node < jb.n)
                jb.cat[(long long)node * jb.cstr + jb.colbase + cq] =
                    __builtin_bit_cast(uint4, acc);
        }
    }
}

// ---------------------------------------------------------------------------
// apply mega-kernel: out = cat @ [WmA;WmB] + xroot @ Wr + b via MFMA 16x16x32.
// Optional fp16 out and/or fp8-e4m3 out (for next layer's gather).
struct ApplyJobs {
    const uint4* cat[4]; const uint4* xr[4]; const uint4* Bimg[4];
    const float* bA[4]; const float* bB[4];
    ushort* out[4]; uchar* out8[4];
    int cat_kt[4]; int cstr4[4]; int n[4]; int relu[4]; int blk_end[4];
};
__global__ __launch_bounds__(256) void apply_kernel(ApplyJobs a, int njobs) {
    int b = blockIdx.x, j = 0;
    while (b >= a.blk_end[j]) ++j;
    int b0 = j ? a.blk_end[j - 1] : 0;
    int jb = a.blk_end[j] - b0;
    int n = a.n[j], cat_kt = a.cat_kt[j], cstr4 = a.cstr4[j], relu = a.relu[j];
    int K_kt = cat_kt + 2;
    const uint4* cat = a.cat[j];
    const uint4* xr = a.xr[j];
    const uint4* Bimg = a.Bimg[j];
    const float* bA = a.bA[j];
    const float* bB = a.bB[j];
    ushort* out = a.out[j];
    uchar* out8 = a.out8[j];
    int tid = threadIdx.x;
    int w = tid >> 6, lane = tid & 63;
    int mrow = lane & 15, koct = lane >> 4;
    int tiles = (n + 15) >> 4;
    for (int t = (b - b0) * 4 + w; t < tiles; t += jb * 4) {
        int m0 = t << 4;
        int row = m0 + mrow;
        if (row > n - 1) row = n - 1;
        f32x4 acc0 = {0.f, 0.f, 0.f, 0.f};
        f32x4 acc1 = {0.f, 0.f, 0.f, 0.f};
        f32x4 acc2 = {0.f, 0.f, 0.f, 0.f};
        f32x4 acc3 = {0.f, 0.f, 0.f, 0.f};
        for (int kt = 0; kt < K_kt; ++kt) {
            uint4 av;
            if (kt < cat_kt) av = cat[(long long)row * cstr4 + kt * 4 + koct];
            else av = xr[(long long)row * 8 + (kt - cat_kt) * 4 + koct];
            half8 af = __builtin_bit_cast(half8, av);
            const uint4* bp = Bimg + kt * 256 + lane;
            half8 b0f = __builtin_bit_cast(half8, bp[0]);
            half8 b1f = __builtin_bit_cast(half8, bp[64]);
            half8 b2f = __builtin_bit_cast(half8, bp[128]);
            half8 b3f = __builtin_bit_cast(half8, bp[192]);
            acc0 = __builtin_amdgcn_mfma_f32_16x16x32_f16(af, b0f, acc0, 0, 0, 0);
            acc1 = __builtin_amdgcn_mfma_f32_16x16x32_f16(af, b1f, acc1, 0, 0, 0);
            acc2 = __builtin_amdgcn_mfma_f32_16x16x32_f16(af, b2f, acc2, 0, 0, 0);
            acc3 = __builtin_amdgcn_mfma_f32_16x16x32_f16(af, b3f, acc3, 0, 0, 0);
        }
        int c = lane & 15, r0 = m0 + (lane >> 4) * 4;
        f32x4 accs[4] = {acc0, acc1, acc2, acc3};
#pragma unroll
        for (int nt = 0; nt < 4; ++nt) {
            int col = nt * 16 + c;
            float bias = bA[col] + (bB ? bB[col] : 0.f);
#pragma unroll
            for (int r = 0; r < 4; ++r) {
                int rw = r0 + r;
                if (rw < n) {
                    float v = accs[nt][r] + bias;
                    if (relu) v = fmaxf(v, 0.f);
                    if (out) out[(long long)rw * 64 + col] =
                        __builtin_bit_cast(ushort, (_Float16)v);
                    if (out8) out8[(long long)rw * 64 + col] = (uchar)enc1_fp8(v);
                }
            }
        }
    }
}

// ---------------------------------------------------------------------------
// classifier on fp16 tables with packed Wc1 + dot2
__global__ __launch_bounds__(256) void classifier_kernel(
        const ushort* __restrict__ xc, const ushort* __restrict__ xg,
        const int* __restrict__ pd, const int* __restrict__ pg,
        const uint2* __restrict__ gW1, const float* __restrict__ bc1,
        const float* __restrict__ Wc2, const float* __restrict__ bc2,
        float* __restrict__ out, int n) {
    __shared__ uint2 sW1[2048];
    __shared__ float sW2[256];
    __shared__ uint2 shp[4][32];
    __shared__ float sh1[4][65];
    int tid = threadIdx.x;
    for (int t = tid; t < 2048; t += 256) sW1[t] = gW1[t];
    if (tid < 256) sW2[tid] = Wc2[tid];
    __syncthreads();
    int lane = tid & 63, sub = tid >> 6;
    float b1 = bc1[lane];
    const uint* xcp = (const uint*)xc;
    const uint* xgp = (const uint*)xg;
    for (int base = blockIdx.x * 4; base < n; base += gridDim.x * 4) {
        int p = base + sub;
        if (p >= n) continue;
        int dp = pd[p], gp = pg[p];
        uint v = (lane < 32) ? xcp[(long long)dp * 32 + lane]
                             : xgp[(long long)gp * 32 + (lane - 32)];
        ((uint*)&shp[sub][0])[lane] = v;
        float acc = b1;
#pragma unroll
        for (int k4 = 0; k4 < 32; ++k4) {
            uint2 wv = sW1[k4 * 64 + lane];
            uint2 mv = shp[sub][k4];
            acc = fdot2u(mv.x, wv.x, acc);
            acc = fdot2u(mv.y, wv.y, acc);
        }
        sh1[sub][lane] = fmaxf(acc, 0.f);
        if (lane < 4) {
            float a2 = bc2[lane];
#pragma unroll 16
            for (int k = 0; k < 64; ++k) a2 += sh1[sub][k] * sW2[k * 4 + lane];
            out[(long long)p * 4 + lane] = a2;
        }
    }
}

// ---------------------------------------------------------------------------
extern "C" void kernel_launch(void* const* d_in, const int* in_sizes, int n_in,
                              void* d_out, int out_size, void* d_ws, size_t ws_size,
                              hipStream_t stream) {
    const float* gene = (const float*)d_in[0];
    const float* drug = (const float*)d_in[1];
    const float* pcls = (const float*)d_in[2];
    const float* famb = (const float*)d_in[3];
    const float* Wm   = (const float*)d_in[4];
    const float* bm   = (const float*)d_in[5];
    const float* Wr   = (const float*)d_in[6];
    const float* Wc1  = (const float*)d_in[7];
    const float* bc1  = (const float*)d_in[8];
    const float* Wc2  = (const float*)d_in[9];
    const float* bc2  = (const float*)d_in[10];
    const int* ecg_s = (const int*)d_in[11];
    const int* ecg_d = (const int*)d_in[12];
    const int* egc_s = (const int*)d_in[13];
    const int* egc_d = (const int*)d_in[14];
    const int* ecp_s = (const int*)d_in[15];
    const int* ecp_d = (const int*)d_in[16];
    const int* epc_s = (const int*)d_in[17];
    const int* epc_d = (const int*)d_in[18];
    const int* egf_s = (const int*)d_in[19];
    const int* egf_d = (const int*)d_in[20];
    const int* efg_s = (const int*)d_in[21];
    const int* efg_d = (const int*)d_in[22];
    const int* pair_d = (const int*)d_in[23];
    const int* pair_g = (const int*)d_in[24];
    const int E_CG = in_sizes[11];
    const int E_CP = in_sizes[15];
    const int E_GF = in_sizes[19];
    const int N_PAIRS = in_sizes[23];
    const long long TOT_E = 2LL * E_CG + 2LL * E_CP + 2LL * E_GF;

    // ---- workspace layout ----
    ushort* g16   = (ushort*)d_ws;                       // also x2g
    ushort* d16   = g16   + (long long)NG * DD;          // also x2c
    ushort* p16   = d16   + (long long)ND * DD;
    ushort* f16b  = p16   + (long long)NC * DD;
    ushort* x1g16 = f16b  + (long long)NF * DD;
    ushort* x1c16 = x1g16 + (long long)NG * DD;
    ushort* x1p16 = x1c16 + (long long)ND * DD;
    ushort* x1f16 = x1p16 + (long long)NC * DD;
    ushort* x2g16 = g16;
    ushort* x2c16 = d16;
    uint2* pwWc1 = (uint2*)(x1f16 + (long long)NF * DD); // 2048 uint2
    uint4* bimg = (uint4*)(pwWc1 + 2048);                // 6*1536 uint4
    int* ghist = (int*)(bimg + 6 * 1536);                // TOTB
    int* gbinstart = ghist + TOTB;                       // TOTB+1
    int* gcursor = gbinstart + TOTB + 1;                 // TOTB
    int* off_cg = gcursor + TOTB;                        // NG+1
    int* off_gc = off_cg + NG + 1;
    int* off_cp = off_gc + ND + 1;
    int* off_pc = off_cp + NC + 1;
    int* off_gf = off_pc + ND + 1;
    int* off_fg = off_gf + NF + 1;
    long long binned_off = (long long)(off_fg + NG + 1 - (int*)d_ws);
    binned_off = (binned_off + 3) & ~3LL;                // 16B align
    int* binned = (int*)d_ws + binned_off;               // TOT_E ints
    int* adj    = binned + TOT_E;                        // TOT_E ints
    // cat_c/p/f alias binned (dead after csrD); cat_g after adj
    uint4* cat_c = (uint4*)binned;                       // ND*16
    uint4* cat_p = cat_c + (long long)ND * 16;           // NC*8
    uint4* cat_f = cat_p + (long long)NC * 8;            // NF*8
    uint4* cat_g = (uint4*)(adj + TOT_E);                // NG*16
    // fp8 tables after cat_g; x1 fp8 aliases them (inputs dead after L0 gather)
    uchar* g8  = (uchar*)(cat_g + (long long)NG * 16);   // NG*64
    uchar* d8v = g8  + (long long)NG * DD;               // ND*64
    uchar* x1g8 = g8;
    uchar* x1c8 = d8v;

    auto WmLR = [&](int l, int r) { return Wm + (long long)(l * 6 + r) * DD * DD; };
    auto WrLR = [&](int l, int r) { return Wr + (long long)(l * 6 + r) * DD * DD; };
    auto bmLR = [&](int l, int r) { return bm + (long long)(l * 6 + r) * DD; };

    // ---- edge jobs ----
    EdgeJobs ej;
    const int* srcs[NREL] = {ecg_s, egc_s, ecp_s, epc_s, egf_s, efg_s};
    const int* dsts[NREL] = {ecg_d, egc_d, ecp_d, epc_d, egf_d, efg_d};
    int Es[NREL] = {E_CG, E_CG, E_CP, E_CP, E_GF, E_GF};
    int bb[NREL] = {0, NB_CG, NB_CG + NB_GC, NB_CG + NB_GC + NB_CP,
                    NB_CG + NB_GC + NB_CP + NB_PC, NB_CG + NB_GC + NB_CP + NB_PC + NB_GF};
    int acc_blocks = 0;
    for (int j = 0; j < NREL; ++j) {
        ej.src[j] = srcs[j]; ej.dst[j] = dsts[j];
        ej.E[j] = Es[j]; ej.binbase[j] = bb[j];
        acc_blocks += (Es[j] + CHUNK - 1) / CHUNK;
        ej.blk_end[j] = acc_blocks;
    }
    const int THIST = acc_blocks;
    const int CVTB = 1024;

    // ---- pass A: hist + cvt (f16 + fp8 for gene/drug) + packs ----
    (void)hipMemsetAsync(ghist, 0, TOTB * sizeof(int), stream);
    MegaA ma;
    ma.ej = ej;
    ma.cv.in[0] = gene; ma.cv.out[0] = (uint*)g16;  ma.cv.out8[0] = (ushort*)g8;  ma.cv.n2[0] = NG * DD / 2;
    ma.cv.in[1] = drug; ma.cv.out[1] = (uint*)d16;  ma.cv.out8[1] = (ushort*)d8v; ma.cv.n2[1] = ND * DD / 2;
    ma.cv.in[2] = pcls; ma.cv.out[2] = (uint*)p16;  ma.cv.out8[2] = nullptr;      ma.cv.n2[2] = NC * DD / 2;
    ma.cv.in[3] = famb; ma.cv.out[3] = (uint*)f16b; ma.cv.out8[3] = nullptr;      ma.cv.n2[3] = NF * DD / 2;
    ma.Wc1 = Wc1; ma.pwWc1 = pwWc1;
    auto setbp = [&](int j, const float* A, const float* B, const float* Ra, const float* Rb, int nkt) {
        ma.bp.A[j] = A; ma.bp.B[j] = B; ma.bp.Ra[j] = Ra; ma.bp.Rb[j] = Rb;
        ma.bp.out[j] = bimg + j * 1536; ma.bp.nkt[j] = nkt;
    };
    setbp(0, WmLR(0, 0), WmLR(0, 5), WrLR(0, 0), WrLR(0, 5), 6);
    setbp(1, WmLR(0, 1), WmLR(0, 3), WrLR(0, 1), WrLR(0, 3), 6);
    setbp(2, WmLR(0, 2), nullptr,    WrLR(0, 2), nullptr,    4);
    setbp(3, WmLR(0, 4), nullptr,    WrLR(0, 4), nullptr,    4);
    setbp(4, WmLR(1, 0), WmLR(1, 5), WrLR(1, 0), WrLR(1, 5), 6);
    setbp(5, WmLR(1, 1), WmLR(1, 3), WrLR(1, 1), WrLR(1, 3), 6);
    ma.hist_blocks = THIST; ma.cvt_blocks = CVTB;
    ma.ghist = ghist;
    megaA_kernel<<<THIST + CVTB + 1 + 6, 256, 0, stream>>>(ma);

    // ---- passes B, C, D ----
    scanB_kernel<<<1, 64, 0, stream>>>(ghist, gbinstart, gcursor);
    scatC_kernel<<<THIST, 256, 0, stream>>>(ej, gcursor, binned);
    BinMeta bmt;
    int rb[NREL + 1] = {0, NB_CG, NB_CG + NB_GC, NB_CG + NB_GC + NB_CP,
                        NB_CG + NB_GC + NB_CP + NB_PC,
                        NB_CG + NB_GC + NB_CP + NB_PC + NB_GF, TOTB};
    int* offs[NREL] = {off_cg, off_gc, off_cp, off_pc, off_gf, off_fg};
    int nds[NREL] = {NG, ND, NC, ND, NF, NG};
    for (int j = 0; j <= NREL; ++j) bmt.relbase[j] = rb[j];
    for (int j = 0; j < NREL; ++j) { bmt.off[j] = offs[j]; bmt.ndst[j] = nds[j]; }
    csrD_kernel<<<TOTB, 256, 0, stream>>>(bmt, gbinstart, binned, adj);

    auto ablk = [](int n) { int b = ((n + 15) / 16 + 3) / 4; return b > 1024 ? 1024 : b; };
    auto setjb = [](GSched& g, int j, const int* off, const void* x, uint4* cat,
                    int cstr, int colbase, int n, int mode) {
        g.jb[j].off = off; g.jb[j].x = x; g.jb[j].cat = cat;
        g.jb[j].cstr = cstr; g.jb[j].colbase = colbase; g.jb[j].n = n; g.jb[j].mode = mode;
    };

    // ---- layer 0: gather (XCD-segregated) then apply ----
    {
        GSched g;
        setjb(g, 0, off_cg, d8v,  cat_g, 16, 0, NG, 0);  // CG pair, reads d8v (grp A)
        setjb(g, 1, off_fg, f16b, cat_g, 16, 8, NG, 1);  // FG oct, f16b (grp A)
        setjb(g, 2, off_gc, g8,   cat_c, 16, 0, ND, 0);  // GC pair, reads g8 (grp B)
        setjb(g, 3, off_pc, p16,  cat_c, 16, 8, ND, 1);  // PC oct, p16 (grp A)
        setjb(g, 4, off_cp, d8v,  cat_p, 8, 0, NC, 0);   // CP pair, d8v (grp A)
        setjb(g, 5, off_gf, g8,   cat_f, 8, 0, NF, 0);   // GF pair, g8 (grp B)
        int ja[4] = {0, 4, 3, 1}, ea[4] = {106, 111, 116, NSLOT};
        int jbv[4] = {2, 5, -1, -1}, ebv[4] = {116, NSLOT, NSLOT, NSLOT};
        for (int q = 0; q < 4; ++q) {
            g.gjobs[0][q] = ja[q]; g.gend[0][q] = ea[q];
            g.gjobs[1][q] = jbv[q]; g.gend[1][q] = ebv[q];
        }
        gather_kernel<<<8 * NSLOT, 256, 0, stream>>>(g, adj);

        ApplyJobs ap;
        auto seta = [&](int j, const uint4* cat, int ckt, int cstr4, const ushort* xr,
                        const uint4* Bi, const float* biA, const float* biB,
                        ushort* out, uchar* out8, int n, int relu) {
            ap.cat[j] = cat; ap.cat_kt[j] = ckt; ap.cstr4[j] = cstr4;
            ap.xr[j] = (const uint4*)xr; ap.Bimg[j] = Bi; ap.bA[j] = biA; ap.bB[j] = biB;
            ap.out[j] = out; ap.out8[j] = out8; ap.n[j] = n; ap.relu[j] = relu;
        };
        seta(0, cat_g, 4, 16, g16,  bimg + 0 * 1536, bmLR(0, 0), bmLR(0, 5), x1g16, x1g8, NG, 1);
        seta(1, cat_c, 4, 16, d16,  bimg + 1 * 1536, bmLR(0, 1), bmLR(0, 3), x1c16, x1c8, ND, 1);
        seta(2, cat_p, 2, 8,  p16,  bimg + 2 * 1536, bmLR(0, 2), nullptr,    x1p16, nullptr, NC, 1);
        seta(3, cat_f, 2, 8,  f16b, bimg + 3 * 1536, bmLR(0, 4), nullptr,    x1f16, nullptr, NF, 1);
        int acc2 = 0;
        for (int j = 0; j < 4; ++j) { acc2 += ablk(ap.n[j]); ap.blk_end[j] = acc2; }
        apply_kernel<<<acc2, 256, 0, stream>>>(ap, 4);
    }

    // ---- layer 1: gather (XCD-segregated) then apply ----
    {
        GSched g;
        setjb(g, 0, off_cg, x1c8,  cat_g, 16, 0, NG, 0);  // reads x1c8 (grp A)
        setjb(g, 1, off_fg, x1f16, cat_g, 16, 8, NG, 1);  // x1f16 (grp B)
        setjb(g, 2, off_gc, x1g8,  cat_c, 16, 0, ND, 0);  // reads x1g8 (grp B)
        setjb(g, 3, off_pc, x1p16, cat_c, 16, 8, ND, 1);  // x1p16 (grp A)
        setjb(g, 4, nullptr, nullptr, nullptr, 8, 0, 0, 0);
        setjb(g, 5, nullptr, nullptr, nullptr, 8, 0, 0, 0);
        int ja[4] = {0, 3, -1, -1}, ea[4] = {118, NSLOT, NSLOT, NSLOT};
        int jbv[4] = {2, 1, -1, -1}, ebv[4] = {116, NSLOT, NSLOT, NSLOT};
        for (int q = 0; q < 4; ++q) {
            g.gjobs[0][q] = ja[q]; g.gend[0][q] = ea[q];
            g.gjobs[1][q] = jbv[q]; g.gend[1][q] = ebv[q];
        }
        gather_kernel<<<8 * NSLOT, 256, 0, stream>>>(g, adj);

        ApplyJobs ap;
        ap.cat[0] = cat_g; ap.cat_kt[0] = 4; ap.cstr4[0] = 16;
        ap.xr[0] = (const uint4*)x1g16; ap.Bimg[0] = bimg + 4 * 1536;
        ap.bA[0] = bmLR(1, 0); ap.bB[0] = bmLR(1, 5);
        ap.out[0] = x2g16; ap.out8[0] = nullptr; ap.n[0] = NG; ap.relu[0] = 0;
        ap.cat[1] = cat_c; ap.cat_kt[1] = 4; ap.cstr4[1] = 16;
        ap.xr[1] = (const uint4*)x1c16; ap.Bimg[1] = bimg + 5 * 1536;
        ap.bA[1] = bmLR(1, 1); ap.bB[1] = bmLR(1, 3);
        ap.out[1] = x2c16; ap.out8[1] = nullptr; ap.n[1] = ND; ap.relu[1] = 0;
        for (int j = 2; j < 4; ++j) {
            ap.cat[j] = nullptr; ap.xr[j] = nullptr; ap.Bimg[j] = nullptr;
            ap.bA[j] = nullptr; ap.bB[j] = nullptr; ap.out[j] = nullptr; ap.out8[j] = nullptr;
            ap.n[j] = 0; ap.relu[j] = 0; ap.cat_kt[j] = 2; ap.cstr4[j] = 8;
        }
        int acc2 = ablk(NG); ap.blk_end[0] = acc2; acc2 += ablk(ND); ap.blk_end[1] = acc2;
        ap.blk_end[2] = acc2; ap.blk_end[3] = acc2;
        apply_kernel<<<acc2, 256, 0, stream>>>(ap, 2);
    }

    // ---- classifier ----
    int cblocks = (N_PAIRS + 3) / 4;
    if (cblocks > 2048) cblocks = 2048;
    classifier_kernel<<<cblocks, 256, 0, stream>>>(x2c16, x2g16, pair_d, pair_g,
                                                   pwWc1, bc1, Wc2, bc2,
                                                   (float*)d_out, N_PAIRS);
}

// Round 13
// 476.038 us; speedup vs baseline: 1.2912x; 1.2912x over previous
//
#include <hip/hip_runtime.h>
#include <hip/hip_bf16.h>

#define NG 100000
#define ND 50000
#define NC 2000
#define NF 5000
#define DD 64

#define BSH 9
#define BINW 512
#define NREL 6
#define NB_CG ((NG + BINW - 1) / BINW)
#define NB_GC ((ND + BINW - 1) / BINW)
#define NB_CP ((NC + BINW - 1) / BINW)
#define NB_PC ((ND + BINW - 1) / BINW)
#define NB_GF ((NF + BINW - 1) / BINW)
#define NB_FG ((NG + BINW - 1) / BINW)
#define TOTB (NB_CG + NB_GC + NB_CP + NB_PC + NB_GF + NB_FG)
#define CHUNK 4096

typedef _Float16 h2_t __attribute__((ext_vector_type(2)));
typedef _Float16 half8 __attribute__((ext_vector_type(8)));
typedef float f32x4 __attribute__((ext_vector_type(4)));

__device__ inline uint packh2_rne(float a, float b) {
    h2_t h; h.x = (_Float16)a; h.y = (_Float16)b;
    return __builtin_bit_cast(uint, h);
}
__device__ inline uint packh2(float a, float b) {  // RTZ, 1 instr
    return __builtin_bit_cast(uint, __builtin_amdgcn_cvt_pkrtz(a, b));
}
__device__ inline float2 h2f2(uint u) {
    h2_t h = __builtin_bit_cast(h2_t, u);
    return make_float2((float)h.x, (float)h.y);
}
__device__ inline float fdot2u(uint m, uint w, float acc) {
#if __has_builtin(__builtin_amdgcn_fdot2)
    return __builtin_amdgcn_fdot2(__builtin_bit_cast(h2_t, m),
                                  __builtin_bit_cast(h2_t, w), acc, false);
#else
    float2 a = h2f2(m), b = h2f2(w);
    return acc + a.x * b.x + a.y * b.y;
#endif
}

// ---------------------------------------------------------------------------
struct Cvt4 { const float* in[4]; uint* out[4]; int n2[4]; };
struct EdgeJobs {
    const int* src[NREL]; const int* dst[NREL];
    int binbase[NREL]; int E[NREL]; int blk_end[NREL];
};
struct BPackJobs {
    const float* A[6]; const float* B[6]; const float* Ra[6]; const float* Rb[6];
    uint4* out[6]; int nkt[6];
};

// ---------------------------------------------------------------------------
// Mega pass A: edge bin-histogram | f32->f16 table cvt | Wc1 dot2 pack |
// MFMA B-image packs.
struct MegaA {
    EdgeJobs ej; Cvt4 cv; BPackJobs bp;
    const float* Wc1; uint2* pwWc1;
    int hist_blocks, cvt_blocks;
    int* ghist;
};
__global__ __launch_bounds__(256) void megaA_kernel(MegaA a) {
    int b = blockIdx.x;
    if (b < a.hist_blocks) {
        __shared__ int lh[TOTB];
        for (int t = threadIdx.x; t < TOTB; t += 256) lh[t] = 0;
        __syncthreads();
        int j = 0;
        while (b >= a.ej.blk_end[j]) ++j;
        int b0 = j ? a.ej.blk_end[j - 1] : 0;
        int e0 = (b - b0) * CHUNK;
        const int* dst = a.ej.dst[j];
        int E = a.ej.E[j], bb = a.ej.binbase[j];
        for (int t = threadIdx.x; t < CHUNK; t += 256) {
            int e = e0 + t;
            if (e < E) atomicAdd(&lh[bb + (dst[e] >> BSH)], 1);
        }
        __syncthreads();
        for (int t = threadIdx.x; t < TOTB; t += 256)
            if (lh[t]) atomicAdd(&a.ghist[t], lh[t]);
    } else if (b < a.hist_blocks + a.cvt_blocks) {
        int cb = b - a.hist_blocks;
        for (int j = 0; j < 4; ++j) {
            int n2 = a.cv.n2[j];
            const float2* ip = (const float2*)a.cv.in[j];
            uint* op = a.cv.out[j];
            for (int i = cb * 256 + threadIdx.x; i < n2; i += a.cvt_blocks * 256)
                op[i] = packh2_rne(ip[i].x, ip[i].y);
        }
    } else if (b == a.hist_blocks + a.cvt_blocks) {
        // classifier Wc1 pack (dot2 layout): [k4][64] uint2
        const float* A = a.Wc1;
        uint2* o = a.pwWc1;
        for (int t = threadIdx.x; t < 32 * 64; t += 256) {
            int k4 = t >> 6, c = t & 63;
            float v0 = A[(4 * k4 + 0) * 64 + c];
            float v1 = A[(4 * k4 + 1) * 64 + c];
            float v2 = A[(4 * k4 + 2) * 64 + c];
            float v3 = A[(4 * k4 + 3) * 64 + c];
            o[t] = make_uint2(packh2_rne(v0, v1), packh2_rne(v2, v3));
        }
    } else {
        // MFMA B-image pack: out[(kt*4+nt)*64+l] holds 8 f16:
        //   Wcat[kt*32+(l>>4)*8+j][nt*16+(l&15)]
        int pj = b - a.hist_blocks - a.cvt_blocks - 1;
        const float* A = a.bp.A[pj];
        const float* B = a.bp.B[pj];
        const float* Ra = a.bp.Ra[pj];
        const float* Rb = a.bp.Rb[pj];
        uint4* o = a.bp.out[pj];
        int n = a.bp.nkt[pj] * 4 * 64;
        for (int t = threadIdx.x; t < n; t += 256) {
            int kt = t >> 8, nt = (t >> 6) & 3, l = t & 63;
            int col = nt * 16 + (l & 15);
            float v[8];
#pragma unroll
            for (int j = 0; j < 8; ++j) {
                int k = kt * 32 + ((l >> 4) << 3) + j;
                int sel = k >> 6, r = k & 63;
                float x;
                if (sel == 0) x = A[r * 64 + col];
                else if (sel == 1 && B) x = B[r * 64 + col];
                else x = Ra[r * 64 + col] + (Rb ? Rb[r * 64 + col] : 0.f);
                v[j] = x;
            }
            o[t] = make_uint4(packh2_rne(v[0], v[1]), packh2_rne(v[2], v[3]),
                              packh2_rne(v[4], v[5]), packh2_rne(v[6], v[7]));
        }
    }
}

// ---------------------------------------------------------------------------
// Pass B: exclusive scan of bin counts (1 block, wave 0)
__global__ void scanB_kernel(const int* __restrict__ ghist, int* __restrict__ gbinstart,
                             int* __restrict__ gcursor) {
    int lane = threadIdx.x;
    if (lane >= 64) return;
    int carry = 0;
    for (int base = 0; base < TOTB; base += 64) {
        int idx = base + lane;
        int v = (idx < TOTB) ? ghist[idx] : 0;
        int ts = v;
        for (int d = 1; d < 64; d <<= 1) { int t = __shfl_up(ts, d); if (lane >= d) ts += t; }
        int excl = carry + ts - v;
        if (idx < TOTB) { gbinstart[idx] = excl; gcursor[idx] = excl; }
        carry += __shfl(ts, 63);
    }
    if (lane == 0) gbinstart[TOTB] = carry;
}

// ---------------------------------------------------------------------------
// Pass C: binned scatter of packed (src<<9 | dstLocal)
__global__ __launch_bounds__(256) void scatC_kernel(EdgeJobs ej, int* __restrict__ gcursor,
                                                    int* __restrict__ binned) {
    __shared__ int lh[TOTB], lbase[TOTB];
    for (int t = threadIdx.x; t < TOTB; t += 256) lh[t] = 0;
    __syncthreads();
    int b = blockIdx.x, j = 0;
    while (b >= ej.blk_end[j]) ++j;
    int b0 = j ? ej.blk_end[j - 1] : 0;
    int e0 = (b - b0) * CHUNK;
    const int* dst = ej.dst[j];
    const int* srcp = ej.src[j];
    int E = ej.E[j], bb = ej.binbase[j];
    for (int t = threadIdx.x; t < CHUNK; t += 256) {
        int e = e0 + t;
        if (e < E) atomicAdd(&lh[bb + (dst[e] >> BSH)], 1);
    }
    __syncthreads();
    for (int t = threadIdx.x; t < TOTB; t += 256) {
        int c = lh[t];
        if (c) { lbase[t] = atomicAdd(&gcursor[t], c); lh[t] = 0; }
    }
    __syncthreads();
    for (int t = threadIdx.x; t < CHUNK; t += 256) {
        int e = e0 + t;
        if (e < E) {
            int d = dst[e];
            int bin = bb + (d >> BSH);
            int p = atomicAdd(&lh[bin], 1);
            binned[lbase[bin] + p] = (srcp[e] << BSH) | (d & (BINW - 1));
        }
    }
}

// ---------------------------------------------------------------------------
// Pass D: per-bin exact CSR
struct BinMeta { int relbase[NREL + 1]; int* off[NREL]; int ndst[NREL]; };
__global__ __launch_bounds__(256) void csrD_kernel(BinMeta bmt, const int* __restrict__ gbinstart,
                                                   const int* __restrict__ binned,
                                                   int* __restrict__ adj) {
    __shared__ int lcnt[BINW], lexc[BINW];
    int b = blockIdx.x, j = 0;
    while (b >= bmt.relbase[j + 1]) ++j;
    int lb = b - bmt.relbase[j];
    int n0 = lb << BSH;
    int nn = bmt.ndst[j] - n0; if (nn > BINW) nn = BINW;
    int es = gbinstart[b], ee = gbinstart[b + 1];
    for (int t = threadIdx.x; t < BINW; t += 256) lcnt[t] = 0;
    __syncthreads();
    for (int t = es + threadIdx.x; t < ee; t += 256)
        atomicAdd(&lcnt[binned[t] & (BINW - 1)], 1);
    __syncthreads();
    if (threadIdx.x < 64) {
        int lane = threadIdx.x, carry = 0;
        for (int base = 0; base < BINW; base += 64) {
            int v = lcnt[base + lane];
            int ts = v;
            for (int d = 1; d < 64; d <<= 1) { int t2 = __shfl_up(ts, d); if (lane >= d) ts += t2; }
            lexc[base + lane] = carry + ts - v;
            carry += __shfl(ts, 63);
        }
    }
    __syncthreads();
    int* off = bmt.off[j];
    for (int t = threadIdx.x; t < nn; t += 256) off[n0 + t] = es + lexc[t];
    if (threadIdx.x == 0 && n0 + nn == bmt.ndst[j]) off[bmt.ndst[j]] = ee;
    for (int t = threadIdx.x; t < BINW; t += 256) lcnt[t] = 0;
    __syncthreads();
    for (int t = es + threadIdx.x; t < ee; t += 256) {
        int v = binned[t];
        int dl = v & (BINW - 1);
        int p = atomicAdd(&lcnt[dl], 1);
        adj[es + lexc[dl] + p] = v >> BSH;
    }
}

// ---------------------------------------------------------------------------
// dual-node gather+mean (CSR), wave-uniform small-degree fast path
__device__ inline void gather2(const int* __restrict__ off, const int* __restrict__ adj,
                               const uint2* __restrict__ xp,
                               int ia, bool hb, int rg, int cq,
                               float4& ma, float4& mb) {
    int a0 = off[ia], a1 = off[ia + 1];
    int b1v = hb ? off[ia + 2] : a1;
    int na = a1 - a0, nb = b1v - a1;
    const int* Ba = adj + a0;
    const int* Bb = adj + a1;
    float4 sa = {0.f, 0.f, 0.f, 0.f}, sb = {0.f, 0.f, 0.f, 0.f};
    int mx = na > nb ? na : nb;
    if (mx <= 8) {
        for (int j = 0; j < mx; j += 4) {
            int e = j + rg;
            if (j < na) {
                int l = na - 1;
                int s0 = Ba[e < l ? e : l];
                uint2 v0 = xp[(long long)s0 * 16 + cq];
                if (e < na) { float2 lo = h2f2(v0.x), hi = h2f2(v0.y); sa.x += lo.x; sa.y += lo.y; sa.z += hi.x; sa.w += hi.y; }
            }
            if (j < nb) {
                int l = nb - 1;
                int s0 = Bb[e < l ? e : l];
                uint2 v0 = xp[(long long)s0 * 16 + cq];
                if (e < nb) { float2 lo = h2f2(v0.x), hi = h2f2(v0.y); sb.x += lo.x; sb.y += lo.y; sb.z += hi.x; sb.w += hi.y; }
            }
        }
    } else {
        for (int j = 0; j < mx; j += 16) {
            int e0 = j + rg, e1 = j + 4 + rg, e2 = j + 8 + rg, e3 = j + 12 + rg;
            if (j < na) {
                int l = na - 1;
                int s0 = Ba[e0 < l ? e0 : l], s1 = Ba[e1 < l ? e1 : l];
                int s2 = Ba[e2 < l ? e2 : l], s3 = Ba[e3 < l ? e3 : l];
                uint2 v0 = xp[(long long)s0 * 16 + cq];
                uint2 v1 = xp[(long long)s1 * 16 + cq];
                uint2 v2 = xp[(long long)s2 * 16 + cq];
                uint2 v3 = xp[(long long)s3 * 16 + cq];
                if (e0 < na) { float2 lo = h2f2(v0.x), hi = h2f2(v0.y); sa.x += lo.x; sa.y += lo.y; sa.z += hi.x; sa.w += hi.y; }
                if (e1 < na) { float2 lo = h2f2(v1.x), hi = h2f2(v1.y); sa.x += lo.x; sa.y += lo.y; sa.z += hi.x; sa.w += hi.y; }
                if (e2 < na) { float2 lo = h2f2(v2.x), hi = h2f2(v2.y); sa.x += lo.x; sa.y += lo.y; sa.z += hi.x; sa.w += hi.y; }
                if (e3 < na) { float2 lo = h2f2(v3.x), hi = h2f2(v3.y); sa.x += lo.x; sa.y += lo.y; sa.z += hi.x; sa.w += hi.y; }
            }
            if (j < nb) {
                int l = nb - 1;
                int s0 = Bb[e0 < l ? e0 : l], s1 = Bb[e1 < l ? e1 : l];
                int s2 = Bb[e2 < l ? e2 : l], s3 = Bb[e3 < l ? e3 : l];
                uint2 v0 = xp[(long long)s0 * 16 + cq];
                uint2 v1 = xp[(long long)s1 * 16 + cq];
                uint2 v2 = xp[(long long)s2 * 16 + cq];
                uint2 v3 = xp[(long long)s3 * 16 + cq];
                if (e0 < nb) { float2 lo = h2f2(v0.x), hi = h2f2(v0.y); sb.x += lo.x; sb.y += lo.y; sb.z += hi.x; sb.w += hi.y; }
                if (e1 < nb) { float2 lo = h2f2(v1.x), hi = h2f2(v1.y); sb.x += lo.x; sb.y += lo.y; sb.z += hi.x; sb.w += hi.y; }
                if (e2 < nb) { float2 lo = h2f2(v2.x), hi = h2f2(v2.y); sb.x += lo.x; sb.y += lo.y; sb.z += hi.x; sb.w += hi.y; }
                if (e3 < nb) { float2 lo = h2f2(v3.x), hi = h2f2(v3.y); sb.x += lo.x; sb.y += lo.y; sb.z += hi.x; sb.w += hi.y; }
            }
        }
    }
    sa.x += __shfl_xor(sa.x, 16); sa.y += __shfl_xor(sa.y, 16);
    sa.z += __shfl_xor(sa.z, 16); sa.w += __shfl_xor(sa.w, 16);
    sa.x += __shfl_xor(sa.x, 32); sa.y += __shfl_xor(sa.y, 32);
    sa.z += __shfl_xor(sa.z, 32); sa.w += __shfl_xor(sa.w, 32);
    sb.x += __shfl_xor(sb.x, 16); sb.y += __shfl_xor(sb.y, 16);
    sb.z += __shfl_xor(sb.z, 16); sb.w += __shfl_xor(sb.w, 16);
    sb.x += __shfl_xor(sb.x, 32); sb.y += __shfl_xor(sb.y, 32);
    sb.z += __shfl_xor(sb.z, 32); sb.w += __shfl_xor(sb.w, 32);
    float inva = 1.f / fmaxf((float)na, 1.f);
    float invb = 1.f / fmaxf((float)nb, 1.f);
    ma.x = sa.x * inva; ma.y = sa.y * inva; ma.z = sa.z * inva; ma.w = sa.w * inva;
    mb.x = sb.x * invb; mb.y = sb.y * invb; mb.z = sb.z * invb; mb.w = sb.w * invb;
}

// ---------------------------------------------------------------------------
// gather mega-kernel: writes fp16 means into concat rows. No LDS.
struct GatherJobs {
    const int* offA[4]; const int* offB[4];
    const uint2* xA[4]; const uint2* xB[4];
    uint2* cat[4]; int cstr[4]; int n[4]; int hasB[4]; int blk_end[4];
};
__global__ __launch_bounds__(256) void gather_kernel(GatherJobs g, const int* __restrict__ adj,
                                                     int njobs) {
    int b = blockIdx.x, j = 0;
    while (b >= g.blk_end[j]) ++j;
    int b0 = j ? g.blk_end[j - 1] : 0;
    int jb = g.blk_end[j] - b0;
    int n = g.n[j], cstr = g.cstr[j], hasB = g.hasB[j];
    const int* offA = g.offA[j];
    const int* offB = g.offB[j];
    const uint2* xA = g.xA[j];
    const uint2* xB = g.xB[j];
    uint2* cat = g.cat[j];
    int tid = threadIdx.x;
    int w = tid >> 6, lane = tid & 63, rg = lane >> 4, cq = lane & 15;
    for (int i0 = (b - b0) * 8; i0 < n; i0 += jb * 8) {
        int ia = i0 + w * 2;
        if (ia >= n) continue;
        int ib = ia + 1;
        bool hb = (ib < n);
        float4 mA0, mA1;
        gather2(offA, adj, xA, ia, hb, rg, cq, mA0, mA1);
        if (rg == 0) {
            cat[(long long)ia * cstr + cq] = make_uint2(packh2(mA0.x, mA0.y), packh2(mA0.z, mA0.w));
            if (hb) cat[(long long)ib * cstr + cq] = make_uint2(packh2(mA1.x, mA1.y), packh2(mA1.z, mA1.w));
        }
        if (hasB) {
            float4 mB0, mB1;
            gather2(offB, adj, xB, ia, hb, rg, cq, mB0, mB1);
            if (rg == 0) {
                cat[(long long)ia * cstr + 16 + cq] = make_uint2(packh2(mB0.x, mB0.y), packh2(mB0.z, mB0.w));
                if (hb) cat[(long long)ib * cstr + 16 + cq] = make_uint2(packh2(mB1.x, mB1.y), packh2(mB1.z, mB1.w));
            }
        }
    }
}

// ---------------------------------------------------------------------------
// apply mega-kernel: out = cat @ [WmA;WmB] + xroot @ Wr + b via MFMA 16x16x32.
struct ApplyJobs {
    const uint4* cat[4]; const uint4* xr[4]; const uint4* Bimg[4];
    const float* bA[4]; const float* bB[4];
    ushort* out[4];
    int cat_kt[4]; int cstr4[4]; int n[4]; int relu[4]; int blk_end[4];
};
__global__ __launch_bounds__(256) void apply_kernel(ApplyJobs a, int njobs) {
    int b = blockIdx.x, j = 0;
    while (b >= a.blk_end[j]) ++j;
    int b0 = j ? a.blk_end[j - 1] : 0;
    int jb = a.blk_end[j] - b0;
    int n = a.n[j], cat_kt = a.cat_kt[j], cstr4 = a.cstr4[j], relu = a.relu[j];
    int K_kt = cat_kt + 2;
    const uint4* cat = a.cat[j];
    const uint4* xr = a.xr[j];
    const uint4* Bimg = a.Bimg[j];
    const float* bA = a.bA[j];
    const float* bB = a.bB[j];
    ushort* out = a.out[j];
    int tid = threadIdx.x;
    int w = tid >> 6, lane = tid & 63;
    int mrow = lane & 15, koct = lane >> 4;
    int tiles = (n + 15) >> 4;
    for (int t = (b - b0) * 4 + w; t < tiles; t += jb * 4) {
        int m0 = t << 4;
        int row = m0 + mrow;
        if (row > n - 1) row = n - 1;
        f32x4 acc0 = {0.f, 0.f, 0.f, 0.f};
        f32x4 acc1 = {0.f, 0.f, 0.f, 0.f};
        f32x4 acc2 = {0.f, 0.f, 0.f, 0.f};
        f32x4 acc3 = {0.f, 0.f, 0.f, 0.f};
        for (int kt = 0; kt < K_kt; ++kt) {
            uint4 av;
            if (kt < cat_kt) av = cat[(long long)row * cstr4 + kt * 4 + koct];
            else av = xr[(long long)row * 8 + (kt - cat_kt) * 4 + koct];
            half8 af = __builtin_bit_cast(half8, av);
            const uint4* bp = Bimg + kt * 256 + lane;
            half8 b0f = __builtin_bit_cast(half8, bp[0]);
            half8 b1f = __builtin_bit_cast(half8, bp[64]);
            half8 b2f = __builtin_bit_cast(half8, bp[128]);
            half8 b3f = __builtin_bit_cast(half8, bp[192]);
            acc0 = __builtin_amdgcn_mfma_f32_16x16x32_f16(af, b0f, acc0, 0, 0, 0);
            acc1 = __builtin_amdgcn_mfma_f32_16x16x32_f16(af, b1f, acc1, 0, 0, 0);
            acc2 = __builtin_amdgcn_mfma_f32_16x16x32_f16(af, b2f, acc2, 0, 0, 0);
            acc3 = __builtin_amdgcn_mfma_f32_16x16x32_f16(af, b3f, acc3, 0, 0, 0);
        }
        int c = lane & 15, r0 = m0 + (lane >> 4) * 4;
        f32x4 accs[4] = {acc0, acc1, acc2, acc3};
#pragma unroll
        for (int nt = 0; nt < 4; ++nt) {
            int col = nt * 16 + c;
            float bias = bA[col] + (bB ? bB[col] : 0.f);
#pragma unroll
            for (int r = 0; r < 4; ++r) {
                int rw = r0 + r;
                if (rw < n) {
                    float v = accs[nt][r] + bias;
                    if (relu) v = fmaxf(v, 0.f);
                    out[(long long)rw * 64 + col] = __builtin_bit_cast(ushort, (_Float16)v);
                }
            }
        }
    }
}

// ---------------------------------------------------------------------------
// classifier on fp16 tables with packed Wc1 + dot2
__global__ __launch_bounds__(256) void classifier_kernel(
        const ushort* __restrict__ xc, const ushort* __restrict__ xg,
        const int* __restrict__ pd, const int* __restrict__ pg,
        const uint2* __restrict__ gW1, const float* __restrict__ bc1,
        const float* __restrict__ Wc2, const float* __restrict__ bc2,
        float* __restrict__ out, int n) {
    __shared__ uint2 sW1[2048];
    __shared__ float sW2[256];
    __shared__ uint2 shp[4][32];
    __shared__ float sh1[4][65];
    int tid = threadIdx.x;
    for (int t = tid; t < 2048; t += 256) sW1[t] = gW1[t];
    if (tid < 256) sW2[tid] = Wc2[tid];
    __syncthreads();
    int lane = tid & 63, sub = tid >> 6;
    float b1 = bc1[lane];
    const uint* xcp = (const uint*)xc;
    const uint* xgp = (const uint*)xg;
    for (int base = blockIdx.x * 4; base < n; base += gridDim.x * 4) {
        int p = base + sub;
        if (p >= n) continue;
        int dp = pd[p], gp = pg[p];
        uint v = (lane < 32) ? xcp[(long long)dp * 32 + lane]
                             : xgp[(long long)gp * 32 + (lane - 32)];
        ((uint*)&shp[sub][0])[lane] = v;
        float acc = b1;
#pragma unroll
        for (int k4 = 0; k4 < 32; ++k4) {
            uint2 wv = sW1[k4 * 64 + lane];
            uint2 mv = shp[sub][k4];
            acc = fdot2u(mv.x, wv.x, acc);
            acc = fdot2u(mv.y, wv.y, acc);
        }
        sh1[sub][lane] = fmaxf(acc, 0.f);
        if (lane < 4) {
            float a2 = bc2[lane];
#pragma unroll 16
            for (int k = 0; k < 64; ++k) a2 += sh1[sub][k] * sW2[k * 4 + lane];
            out[(long long)p * 4 + lane] = a2;
        }
    }
}

// ---------------------------------------------------------------------------
extern "C" void kernel_launch(void* const* d_in, const int* in_sizes, int n_in,
                              void* d_out, int out_size, void* d_ws, size_t ws_size,
                              hipStream_t stream) {
    const float* gene = (const float*)d_in[0];
    const float* drug = (const float*)d_in[1];
    const float* pcls = (const float*)d_in[2];
    const float* famb = (const float*)d_in[3];
    const float* Wm   = (const float*)d_in[4];
    const float* bm   = (const float*)d_in[5];
    const float* Wr   = (const float*)d_in[6];
    const float* Wc1  = (const float*)d_in[7];
    const float* bc1  = (const float*)d_in[8];
    const float* Wc2  = (const float*)d_in[9];
    const float* bc2  = (const float*)d_in[10];
    const int* ecg_s = (const int*)d_in[11];
    const int* ecg_d = (const int*)d_in[12];
    const int* egc_s = (const int*)d_in[13];
    const int* egc_d = (const int*)d_in[14];
    const int* ecp_s = (const int*)d_in[15];
    const int* ecp_d = (const int*)d_in[16];
    const int* epc_s = (const int*)d_in[17];
    const int* epc_d = (const int*)d_in[18];
    const int* egf_s = (const int*)d_in[19];
    const int* egf_d = (const int*)d_in[20];
    const int* efg_s = (const int*)d_in[21];
    const int* efg_d = (const int*)d_in[22];
    const int* pair_d = (const int*)d_in[23];
    const int* pair_g = (const int*)d_in[24];
    const int E_CG = in_sizes[11];
    const int E_CP = in_sizes[15];
    const int E_GF = in_sizes[19];
    const int N_PAIRS = in_sizes[23];
    const long long TOT_E = 2LL * E_CG + 2LL * E_CP + 2LL * E_GF;

    // ---- workspace layout ----
    ushort* g16   = (ushort*)d_ws;                       // also x2g
    ushort* d16   = g16   + (long long)NG * DD;          // also x2c
    ushort* p16   = d16   + (long long)ND * DD;
    ushort* f16b  = p16   + (long long)NC * DD;
    ushort* x1g16 = f16b  + (long long)NF * DD;
    ushort* x1c16 = x1g16 + (long long)NG * DD;
    ushort* x1p16 = x1c16 + (long long)ND * DD;
    ushort* x1f16 = x1p16 + (long long)NC * DD;
    ushort* x2g16 = g16;
    ushort* x2c16 = d16;
    uint2* pwWc1 = (uint2*)(x1f16 + (long long)NF * DD); // 2048 uint2
    uint4* bimg = (uint4*)(pwWc1 + 2048);                // 6*1536 uint4
    int* ghist = (int*)(bimg + 6 * 1536);                // TOTB
    int* gbinstart = ghist + TOTB;                       // TOTB+1
    int* gcursor = gbinstart + TOTB + 1;                 // TOTB
    int* off_cg = gcursor + TOTB;                        // NG+1
    int* off_gc = off_cg + NG + 1;
    int* off_cp = off_gc + ND + 1;
    int* off_pc = off_cp + NC + 1;
    int* off_gf = off_pc + ND + 1;
    int* off_fg = off_gf + NF + 1;
    long long binned_off = (long long)(off_fg + NG + 1 - (int*)d_ws);
    binned_off = (binned_off + 3) & ~3LL;                // 16B align
    int* binned = (int*)d_ws + binned_off;               // TOT_E ints
    int* adj    = binned + TOT_E;                        // TOT_E ints
    // cat buffers: cat_c/p/f alias binned (dead after csrD); cat_g after adj
    uint2* cat_c = (uint2*)binned;                       // ND*32
    uint2* cat_p = cat_c + (long long)ND * 32;           // NC*16
    uint2* cat_f = cat_p + (long long)NC * 16;           // NF*16
    uint2* cat_g = (uint2*)(adj + TOT_E);                // NG*32

    auto WmLR = [&](int l, int r) { return Wm + (long long)(l * 6 + r) * DD * DD; };
    auto WrLR = [&](int l, int r) { return Wr + (long long)(l * 6 + r) * DD * DD; };
    auto bmLR = [&](int l, int r) { return bm + (long long)(l * 6 + r) * DD; };

    // ---- edge jobs ----
    EdgeJobs ej;
    const int* srcs[NREL] = {ecg_s, egc_s, ecp_s, epc_s, egf_s, efg_s};
    const int* dsts[NREL] = {ecg_d, egc_d, ecp_d, epc_d, egf_d, efg_d};
    int Es[NREL] = {E_CG, E_CG, E_CP, E_CP, E_GF, E_GF};
    int bb[NREL] = {0, NB_CG, NB_CG + NB_GC, NB_CG + NB_GC + NB_CP,
                    NB_CG + NB_GC + NB_CP + NB_PC, NB_CG + NB_GC + NB_CP + NB_PC + NB_GF};
    int acc_blocks = 0;
    for (int j = 0; j < NREL; ++j) {
        ej.src[j] = srcs[j]; ej.dst[j] = dsts[j];
        ej.E[j] = Es[j]; ej.binbase[j] = bb[j];
        acc_blocks += (Es[j] + CHUNK - 1) / CHUNK;
        ej.blk_end[j] = acc_blocks;
    }
    const int THIST = acc_blocks;
    const int CVTB = 1024;

    // ---- pass A: hist + cvt + packs ----
    (void)hipMemsetAsync(ghist, 0, TOTB * sizeof(int), stream);
    MegaA ma;
    ma.ej = ej;
    ma.cv.in[0] = gene; ma.cv.out[0] = (uint*)g16;  ma.cv.n2[0] = NG * DD / 2;
    ma.cv.in[1] = drug; ma.cv.out[1] = (uint*)d16;  ma.cv.n2[1] = ND * DD / 2;
    ma.cv.in[2] = pcls; ma.cv.out[2] = (uint*)p16;  ma.cv.n2[2] = NC * DD / 2;
    ma.cv.in[3] = famb; ma.cv.out[3] = (uint*)f16b; ma.cv.n2[3] = NF * DD / 2;
    ma.Wc1 = Wc1; ma.pwWc1 = pwWc1;
    auto setbp = [&](int j, const float* A, const float* B, const float* Ra, const float* Rb, int nkt) {
        ma.bp.A[j] = A; ma.bp.B[j] = B; ma.bp.Ra[j] = Ra; ma.bp.Rb[j] = Rb;
        ma.bp.out[j] = bimg + j * 1536; ma.bp.nkt[j] = nkt;
    };
    setbp(0, WmLR(0, 0), WmLR(0, 5), WrLR(0, 0), WrLR(0, 5), 6);
    setbp(1, WmLR(0, 1), WmLR(0, 3), WrLR(0, 1), WrLR(0, 3), 6);
    setbp(2, WmLR(0, 2), nullptr,    WrLR(0, 2), nullptr,    4);
    setbp(3, WmLR(0, 4), nullptr,    WrLR(0, 4), nullptr,    4);
    setbp(4, WmLR(1, 0), WmLR(1, 5), WrLR(1, 0), WrLR(1, 5), 6);
    setbp(5, WmLR(1, 1), WmLR(1, 3), WrLR(1, 1), WrLR(1, 3), 6);
    ma.hist_blocks = THIST; ma.cvt_blocks = CVTB;
    ma.ghist = ghist;
    megaA_kernel<<<THIST + CVTB + 1 + 6, 256, 0, stream>>>(ma);

    // ---- passes B, C, D ----
    scanB_kernel<<<1, 64, 0, stream>>>(ghist, gbinstart, gcursor);
    scatC_kernel<<<THIST, 256, 0, stream>>>(ej, gcursor, binned);
    BinMeta bmt;
    int rb[NREL + 1] = {0, NB_CG, NB_CG + NB_GC, NB_CG + NB_GC + NB_CP,
                        NB_CG + NB_GC + NB_CP + NB_PC,
                        NB_CG + NB_GC + NB_CP + NB_PC + NB_GF, TOTB};
    int* offs[NREL] = {off_cg, off_gc, off_cp, off_pc, off_gf, off_fg};
    int nds[NREL] = {NG, ND, NC, ND, NF, NG};
    for (int j = 0; j <= NREL; ++j) bmt.relbase[j] = rb[j];
    for (int j = 0; j < NREL; ++j) { bmt.off[j] = offs[j]; bmt.ndst[j] = nds[j]; }
    csrD_kernel<<<TOTB, 256, 0, stream>>>(bmt, gbinstart, binned, adj);

    auto gblk = [](int n) { int b = (n + 7) / 8; return b > 2048 ? 2048 : b; };
    auto ablk = [](int n) { int b = ((n + 15) / 16 + 3) / 4; return b > 1024 ? 1024 : b; };

    // ---- layer 0: gather then apply ----
    {
        GatherJobs g;
        auto setg = [&](int j, const int* oA, const uint2* xA, const int* oB, const uint2* xB,
                        uint2* cat, int cstr, int n, int hb) {
            g.offA[j] = oA; g.offB[j] = oB; g.xA[j] = xA; g.xB[j] = xB;
            g.cat[j] = cat; g.cstr[j] = cstr; g.n[j] = n; g.hasB[j] = hb;
        };
        setg(0, off_cg, (const uint2*)d16, off_fg, (const uint2*)f16b, cat_g, 32, NG, 1);
        setg(1, off_gc, (const uint2*)g16, off_pc, (const uint2*)p16, cat_c, 32, ND, 1);
        setg(2, off_cp, (const uint2*)d16, nullptr, nullptr, cat_p, 16, NC, 0);
        setg(3, off_gf, (const uint2*)g16, nullptr, nullptr, cat_f, 16, NF, 0);
        int acc = 0;
        for (int j = 0; j < 4; ++j) { acc += gblk(g.n[j]); g.blk_end[j] = acc; }
        gather_kernel<<<acc, 256, 0, stream>>>(g, adj, 4);

        ApplyJobs ap;
        auto seta = [&](int j, const uint2* cat, int ckt, int cstr4, const ushort* xr,
                        const uint4* Bi, const float* biA, const float* biB,
                        ushort* out, int n, int relu) {
            ap.cat[j] = (const uint4*)cat; ap.cat_kt[j] = ckt; ap.cstr4[j] = cstr4;
            ap.xr[j] = (const uint4*)xr; ap.Bimg[j] = Bi; ap.bA[j] = biA; ap.bB[j] = biB;
            ap.out[j] = out; ap.n[j] = n; ap.relu[j] = relu;
        };
        seta(0, cat_g, 4, 16, g16,  bimg + 0 * 1536, bmLR(0, 0), bmLR(0, 5), x1g16, NG, 1);
        seta(1, cat_c, 4, 16, d16,  bimg + 1 * 1536, bmLR(0, 1), bmLR(0, 3), x1c16, ND, 1);
        seta(2, cat_p, 2, 8,  p16,  bimg + 2 * 1536, bmLR(0, 2), nullptr,    x1p16, NC, 1);
        seta(3, cat_f, 2, 8,  f16b, bimg + 3 * 1536, bmLR(0, 4), nullptr,    x1f16, NF, 1);
        int acc2 = 0;
        for (int j = 0; j < 4; ++j) { acc2 += ablk(ap.n[j]); ap.blk_end[j] = acc2; }
        apply_kernel<<<acc2, 256, 0, stream>>>(ap, 4);
    }

    // ---- layer 1: gather then apply (gene & compound only) ----
    {
        GatherJobs g;
        g.offA[0] = off_cg; g.offB[0] = off_fg;
        g.xA[0] = (const uint2*)x1c16; g.xB[0] = (const uint2*)x1f16;
        g.cat[0] = cat_g; g.cstr[0] = 32; g.n[0] = NG; g.hasB[0] = 1;
        g.offA[1] = off_gc; g.offB[1] = off_pc;
        g.xA[1] = (const uint2*)x1g16; g.xB[1] = (const uint2*)x1p16;
        g.cat[1] = cat_c; g.cstr[1] = 32; g.n[1] = ND; g.hasB[1] = 1;
        for (int j = 2; j < 4; ++j) { g.offA[j] = nullptr; g.offB[j] = nullptr; g.xA[j] = nullptr; g.xB[j] = nullptr; g.cat[j] = nullptr; g.cstr[j] = 16; g.n[j] = 0; g.hasB[j] = 0; }
        int acc = gblk(NG); g.blk_end[0] = acc; acc += gblk(ND); g.blk_end[1] = acc;
        g.blk_end[2] = acc; g.blk_end[3] = acc;
        gather_kernel<<<acc, 256, 0, stream>>>(g, adj, 2);

        ApplyJobs ap;
        ap.cat[0] = (const uint4*)cat_g; ap.cat_kt[0] = 4; ap.cstr4[0] = 16;
        ap.xr[0] = (const uint4*)x1g16; ap.Bimg[0] = bimg + 4 * 1536;
        ap.bA[0] = bmLR(1, 0); ap.bB[0] = bmLR(1, 5);
        ap.out[0] = x2g16; ap.n[0] = NG; ap.relu[0] = 0;
        ap.cat[1] = (const uint4*)cat_c; ap.cat_kt[1] = 4; ap.cstr4[1] = 16;
        ap.xr[1] = (const uint4*)x1c16; ap.Bimg[1] = bimg + 5 * 1536;
        ap.bA[1] = bmLR(1, 1); ap.bB[1] = bmLR(1, 3);
        ap.out[1] = x2c16; ap.n[1] = ND; ap.relu[1] = 0;
        for (int j = 2; j < 4; ++j) { ap.cat[j] = nullptr; ap.xr[j] = nullptr; ap.Bimg[j] = nullptr; ap.bA[j] = nullptr; ap.bB[j] = nullptr; ap.out[j] = nullptr; ap.n[j] = 0; ap.relu[j] = 0; ap.cat_kt[j] = 2; ap.cstr4[j] = 8; }
        int acc2 = ablk(NG); ap.blk_end[0] = acc2; acc2 += ablk(ND); ap.blk_end[1] = acc2;
        ap.blk_end[2] = acc2; ap.blk_end[3] = acc2;
        apply_kernel<<<acc2, 256, 0, stream>>>(ap, 2);
    }

    // ---- classifier ----
    int cblocks = (N_PAIRS + 3) / 4;
    if (cblocks > 2048) cblocks = 2048;
    classifier_kernel<<<cblocks, 256, 0, stream>>>(x2c16, x2g16, pair_d, pair_g,
                                                   pwWc1, bc1, Wc2, bc2,
                                                   (float*)d_out, N_PAIRS);
}